// Round 7
// baseline (200.488 us; speedup 1.0000x reference)
//
#include <hip/hip_runtime.h>
#include <stdint.h>

// Problem constants (B=16, C=256, H=W=32, K=8192)
#define CCDIM 256
#define HWP 1024
#define NPOS 16384
#define KC 8192
#define NKB 64  // number of 128-code tiles

typedef unsigned short u16;
typedef unsigned int u32;
typedef unsigned long long u64;
typedef __attribute__((ext_vector_type(8))) _Float16 half8;
typedef __attribute__((ext_vector_type(4))) float f32x4;

__device__ __forceinline__ u16 f16bits(float f) {
  _Float16 h = (_Float16)f;  // RNE
  return *(u16*)&h;
}
__device__ __forceinline__ u32 umin2(u32 a, u32 b) { return a < b ? a : b; }
__device__ __forceinline__ u32 umax2(u32 a, u32 b) { return a > b ? a : b; }
__device__ __forceinline__ u64 umin64(u64 a, u64 b) { return a < b ? a : b; }
__device__ __forceinline__ u64 umax64(u64 a, u64 b) { return a > b ? a : b; }
// exact top-2 merge of two sorted pairs (a1<=a2, b1<=b2)
__device__ __forceinline__ void comb(u32& a1, u32& a2, u32 b1, u32 b2) {
  const u32 lo = umin2(a1, b1);
  const u32 hi = umax2(a1, b1);
  a2 = umin2(hi, umin2(a2, b2));
  a1 = lo;
}
// sorted top-4 insert (u64)
__device__ __forceinline__ void ins4(u64& s1, u64& s2, u64& s3, u64& s4,
                                     u64 k) {
  u64 c = umin64(s1, k);
  k = umax64(s1, k);
  s1 = c;
  c = umin64(s2, k);
  k = umax64(s2, k);
  s2 = c;
  c = umin64(s3, k);
  k = umax64(s3, k);
  s3 = c;
  s4 = umin64(s4, k);
}

// global_load_lds, width 16: lane i -> ldsbase + i*16
#define GLD(g, l)                                                   \
  __builtin_amdgcn_global_load_lds(                                 \
      (const __attribute__((address_space(1))) u32*)(g),            \
      (__attribute__((address_space(3))) u32*)(l), 16, 0, 0)

// ---------------------------------------------------------------------------
// pack_all: blocks [0,2048): cb -> ch (f16) + e2 (block 0 zeroes acc/cnt);
// blocks [2048,3072): x -> xh transpose, 1024 tiles of 64 pos x 64 chan
// (4 blocks/CU for latency hiding; R6 used only 256 blocks = 1/CU).
// ---------------------------------------------------------------------------
__global__ __launch_bounds__(256) void pack_all(
    const float* __restrict__ x, const float* __restrict__ cb,
    u16* __restrict__ xh, u16* __restrict__ ch, float* __restrict__ e2,
    float* __restrict__ accp, u32* __restrict__ cntp) {
  __shared__ float tile[64][65];  // 64 pos x 64 chan, 2-way max (free)
  const int t = threadIdx.x, lane = t & 63, w = t >> 6;
  if (blockIdx.x < 2048) {
    // ---- codebook pack + e2 ----
    if (blockIdx.x == 0 && t == 0) {
      accp[0] = 0.0f;
      cntp[0] = 0u;
    }
    const int k = blockIdx.x * 4 + w;
    const float4 v = *(const float4*)(cb + (size_t)k * CCDIM + lane * 4);
    float s = v.x * v.x + v.y * v.y + v.z * v.z + v.w * v.w;
    const u32 w0 = (u32)f16bits(v.x) | ((u32)f16bits(v.y) << 16);
    const u32 w1 = (u32)f16bits(v.z) | ((u32)f16bits(v.w) << 16);
    *(uint2*)(ch + (size_t)k * CCDIM + lane * 4) = make_uint2(w0, w1);
#pragma unroll
    for (int off = 32; off > 0; off >>= 1) s += __shfl_down(s, off, 64);
    if (lane == 0) e2[k] = s;
    return;
  }
  // ---- x pack (transpose), 64 pos x 64 chan per block ----
  const int bid = blockIdx.x - 2048;      // [0,1024)
  const int pc = bid >> 2;                // 256 position chunks of 64
  const int c0 = (bid & 3) * 64;          // 4 channel chunks of 64
  const int b = pc >> 4;
  const int hw0 = (pc & 15) * 64;
  const int p0 = pc * 64;  // = b*1024 + hw0
  // stage: each pass reads 4 channels x 64 consecutive positions (256 B)
#pragma unroll 4
  for (int i = 0; i < 16; ++i) {
    const int cr = w * 16 + i;
    tile[lane][cr] =
        x[(size_t)b * (CCDIM * HWP) + (size_t)(c0 + cr) * HWP + hw0 + lane];
  }
  __syncthreads();
  // emit: thread (r = t>>2, q = t&3) packs 16 channels -> two uint4
  {
    const int r = t >> 2, q = t & 3;
#pragma unroll
    for (int h = 0; h < 2; ++h) {
      const int cl0 = q * 16 + h * 8;
      u32 wd[4];
#pragma unroll
      for (int p = 0; p < 4; ++p)
        wd[p] = (u32)f16bits(tile[r][cl0 + 2 * p]) |
                ((u32)f16bits(tile[r][cl0 + 2 * p + 1]) << 16);
      *(uint4*)(xh + (size_t)(p0 + r) * CCDIM + c0 + cl0) =
          make_uint4(wd[0], wd[1], wd[2], wd[3]);
    }
  }
}

// ---------------------------------------------------------------------------
// gemm_argmin: UNCHANGED from R5/R6 (control). A = codebook, B = x, 128x128,
// BK=64, f16 MFMA, register-local top-2 epilogue, packed u64 partials.
// ---------------------------------------------------------------------------
#define LDS_US (2 * 128 * 64) /* A (ch) + B (xh) tiles, 16 KB each */

__global__ __launch_bounds__(256, 4) void gemm_argmin(
    const u16* __restrict__ xh, const u16* __restrict__ ch,
    const float* __restrict__ e2, u64* __restrict__ part) {
  __shared__ __align__(16) u16 lds[LDS_US];
  __shared__ u32 sv1[128], sv2[128];
  const int tid = threadIdx.x;
  const int w = tid >> 6, lane = tid & 63;
  const int fr = lane & 15, qg = lane >> 4;
  const int p0 = blockIdx.x * 128;  // positions
  const int k0 = blockIdx.y * 128;  // codes
  const int mhalf = (w & 1) * 64;   // code half (A-row offset)
  const int n_off = (w >> 1) * 64;  // position half (B-row offset)

  f32x4 acc[4][4];  // [mf(code tile)][nf(pos tile)]
#pragma unroll
  for (int i = 0; i < 4; ++i)
#pragma unroll
    for (int j = 0; j < 4; ++j) acc[i][j] = (f32x4){0.f, 0.f, 0.f, 0.f};

  size_t offA[4], offB[4];
  int ldso[4];
#pragma unroll
  for (int t = 0; t < 4; ++t) {
    const int s = w * 256 + t * 64 + lane;
    const int r = s >> 3;
    const int lc = (s & 7) ^ (r & 7);
    offA[t] = (size_t)(k0 + r) * CCDIM + lc * 8;
    offB[t] = (size_t)(p0 + r) * CCDIM + lc * 8;
    ldso[t] = (w * 256 + t * 64) * 8;  // u16 index (wave-uniform)
  }

#pragma unroll 1
  for (int kt = 0; kt < 4; ++kt) {
    const int c0 = kt * 64;
#pragma unroll
    for (int t = 0; t < 4; ++t) GLD(ch + offA[t] + c0, &lds[ldso[t]]);
#pragma unroll
    for (int t = 0; t < 4; ++t) GLD(xh + offB[t] + c0, &lds[8192 + ldso[t]]);
    __syncthreads();

#pragma unroll
    for (int st = 0; st < 2; ++st) {
      half8 a[4];
#pragma unroll
      for (int mf = 0; mf < 4; ++mf) {
        const int rl = mhalf + mf * 16 + fr;
        const int pc = (st * 4 + qg) ^ (rl & 7);
        a[mf] = *(const half8*)&lds[rl * 64 + pc * 8];
      }
#pragma unroll
      for (int nf = 0; nf < 4; ++nf) {
        const int rl = n_off + nf * 16 + fr;
        const int pc = (st * 4 + qg) ^ (rl & 7);
        const half8 b = *(const half8*)&lds[8192 + rl * 64 + pc * 8];
#pragma unroll
        for (int mf = 0; mf < 4; ++mf)
          acc[mf][nf] = __builtin_amdgcn_mfma_f32_16x16x32_f16(a[mf], b,
                                                               acc[mf][nf], 0,
                                                               0, 0);
      }
    }
    __syncthreads();
  }

  float e2p[16];
  u32 lid[16];
#pragma unroll
  for (int mf = 0; mf < 4; ++mf)
#pragma unroll
    for (int rr = 0; rr < 4; ++rr) {
      const int l = mhalf + mf * 16 + qg * 4 + rr;
      lid[mf * 4 + rr] = (u32)l;
      e2p[mf * 4 + rr] = e2[k0 + l] + 1024.0f;
    }
  u32 t1[4], t2[4];
#pragma unroll
  for (int nf = 0; nf < 4; ++nf) {
    u32 key[16];
#pragma unroll
    for (int mf = 0; mf < 4; ++mf)
#pragma unroll
      for (int rr = 0; rr < 4; ++rr)
        key[mf * 4 + rr] =
            (__float_as_uint(fmaf(acc[mf][nf][rr], -2.0f, e2p[mf * 4 + rr])) &
             0xFFFFFF80u) |
            lid[mf * 4 + rr];
    u32 a1[8], a2[8];
#pragma unroll
    for (int i = 0; i < 8; ++i) {
      a1[i] = umin2(key[2 * i], key[2 * i + 1]);
      a2[i] = umax2(key[2 * i], key[2 * i + 1]);
    }
#pragma unroll
    for (int i = 0; i < 4; ++i) comb(a1[i], a2[i], a1[i + 4], a2[i + 4]);
    comb(a1[0], a2[0], a1[2], a2[2]);
    comb(a1[1], a2[1], a1[3], a2[3]);
    comb(a1[0], a2[0], a1[1], a2[1]);
    t1[nf] = a1[0];
    t2[nf] = a2[0];
  }
#pragma unroll
  for (int mask = 16; mask <= 32; mask <<= 1) {
#pragma unroll
    for (int nf = 0; nf < 4; ++nf) {
      const u32 o1 = (u32)__shfl_xor((int)t1[nf], mask, 64);
      const u32 o2 = (u32)__shfl_xor((int)t2[nf], mask, 64);
      comb(t1[nf], t2[nf], o1, o2);
    }
  }
  if (qg == 0 && (w & 1) == 1) {
#pragma unroll
    for (int nf = 0; nf < 4; ++nf) {
      const int pl = n_off + nf * 16 + fr;
      sv1[pl] = t1[nf];
      sv2[pl] = t2[nf];
    }
  }
  __syncthreads();
  if (qg == 0 && (w & 1) == 0) {
#pragma unroll
    for (int nf = 0; nf < 4; ++nf) {
      const int pl = n_off + nf * 16 + fr;
      comb(t1[nf], t2[nf], sv1[pl], sv2[pl]);
      part[(size_t)blockIdx.y * NPOS + p0 + pl] = ((u64)t1[nf] << 32) | t2[nf];
    }
  }
}

// ---------------------------------------------------------------------------
// merge_gather(+finalize): 512 blocks x 32 positions. Phase A2 now runs on
// 128 threads (4/pos: merge 2 sub-lists each, then 2 shfl_xor comb rounds)
// instead of R6's 32-thread serial funnel (~450 -> ~90 u64-op depth).
// ---------------------------------------------------------------------------
__global__ __launch_bounds__(256, 4) void merge_gather(
    const u64* __restrict__ part, const float* __restrict__ x,
    const float* __restrict__ cb, const float* __restrict__ e2,
    float* __restrict__ out, float* __restrict__ accp, u32* __restrict__ cntp) {
  __shared__ float xt[32][CCDIM + 1];  // 32.1 KB: x tile, then q tile
  __shared__ u32 ft[32][4];
  __shared__ u32 fi[32];
  __shared__ float wsum[4];
  u64* lt = (u64*)xt;  // overlay: phase-A scratch [32][8][4] u64 (8 KB)

  const int tid = threadIdx.x;
  const int p0 = blockIdx.x * 32;
  const int b = p0 >> 10;
  const int hw0 = p0 & 1023;

  // ---- Phase A1: 8 subs/position scan 8 tiles each -> sorted top-4 ----
  {
    const int p = tid & 31, sub = tid >> 5;  // coalesced part reads
    const int m = p0 + p;
    u64 s1 = ~0ull, s2 = ~0ull, s3 = ~0ull, s4 = ~0ull;
#pragma unroll 2
    for (int kb = sub * 8; kb < sub * 8 + 8; ++kb) {
      const u64 v = part[(size_t)kb * NPOS + m];
      const u32 k1 = (u32)(v >> 32), k2 = (u32)v;
      ins4(s1, s2, s3, s4,
           ((u64)(k1 & 0xFFFFFF80u) << 32) | (u32)(kb * 128 + (k1 & 127u)));
      ins4(s1, s2, s3, s4,
           ((u64)(k2 & 0xFFFFFF80u) << 32) | (u32)(kb * 128 + (k2 & 127u)));
    }
    lt[(p * 8 + sub) * 4 + 0] = s1;
    lt[(p * 8 + sub) * 4 + 1] = s2;
    lt[(p * 8 + sub) * 4 + 2] = s3;
    lt[(p * 8 + sub) * 4 + 3] = s4;
  }
  __syncthreads();
  // ---- Phase A2: 4 threads/pos; merge 2 sub-lists, then shfl-tree ----
  if (tid < 128) {
    const int p = tid >> 2, j = tid & 2 * 2 / 4 * 0 + (tid & 3);  // j = tid&3
    u64 s1 = lt[(p * 8 + 2 * j) * 4 + 0];
    u64 s2 = lt[(p * 8 + 2 * j) * 4 + 1];
    u64 s3 = lt[(p * 8 + 2 * j) * 4 + 2];
    u64 s4 = lt[(p * 8 + 2 * j) * 4 + 3];
#pragma unroll
    for (int e = 0; e < 4; ++e) ins4(s1, s2, s3, s4, lt[(p * 8 + 2 * j + 1) * 4 + e]);
#pragma unroll
    for (int mask = 1; mask <= 2; mask <<= 1) {
      const u64 o1 = (u64)__shfl_xor((long long)s1, mask, 64);
      const u64 o2 = (u64)__shfl_xor((long long)s2, mask, 64);
      const u64 o3 = (u64)__shfl_xor((long long)s3, mask, 64);
      const u64 o4 = (u64)__shfl_xor((long long)s4, mask, 64);
      ins4(s1, s2, s3, s4, o1);
      ins4(s1, s2, s3, s4, o2);
      ins4(s1, s2, s3, s4, o3);
      ins4(s1, s2, s3, s4, o4);
    }
    if (j == 0) {
      ft[p][0] = (u32)(s1 & 8191u);
      ft[p][1] = (u32)(s2 & 8191u);
      ft[p][2] = (u32)(s3 & 8191u);
      ft[p][3] = (u32)(s4 & 8191u);
    }
  }
  __syncthreads();  // lt reads done; xt reuse is now safe

  // ---- stage x tile (coalesced 128 B segments) ----
  {
    const int hwoff = tid & 31, cg = tid >> 5;
    const size_t xbase = (size_t)b * (CCDIM * HWP) + hw0 + hwoff;
#pragma unroll 8
    for (int i = 0; i < 32; ++i) {
      const int c = cg * 32 + i;
      xt[hwoff][c] = x[xbase + (size_t)c * HWP];
    }
  }
  __syncthreads();

  // ---- Phase B: exact f32 dots; 8 threads per position ----
  {
    const int p = tid >> 3, s = tid & 7;  // q = s>>1, half = s&1
    const int ci = (int)ft[p][s >> 1];
    const float* cp = cb + (size_t)ci * CCDIM + (s & 1) * 128;
    const float* xr = &xt[p][(s & 1) * 128];
    float d0 = 0.f, d1 = 0.f;
#pragma unroll
    for (int j = 0; j < 16; ++j) {
      const float4 v = *(const float4*)(cp + j * 8);
      const float4 v2 = *(const float4*)(cp + j * 8 + 4);
      d0 = fmaf(v.x, xr[j * 8 + 0], d0);
      d0 = fmaf(v.y, xr[j * 8 + 1], d0);
      d0 = fmaf(v.z, xr[j * 8 + 2], d0);
      d0 = fmaf(v.w, xr[j * 8 + 3], d0);
      d1 = fmaf(v2.x, xr[j * 8 + 4], d1);
      d1 = fmaf(v2.y, xr[j * 8 + 5], d1);
      d1 = fmaf(v2.z, xr[j * 8 + 6], d1);
      d1 = fmaf(v2.w, xr[j * 8 + 7], d1);
    }
    float dot = d0 + d1;
    dot += __shfl_xor(dot, 1, 64);  // combine C-halves
    const float d = fmaf(-2.0f, dot, e2[ci]);
    const u32 u = __float_as_uint(d);
    const u32 mono = ((int)u < 0) ? ~u : (u | 0x80000000u);
    u64 key = ((u64)mono << 32) | (u32)ci;
    key = umin64(key, (u64)__shfl_xor((long long)key, 2, 64));
    key = umin64(key, (u64)__shfl_xor((long long)key, 4, 64));
    if (s == 0) fi[p] = (u32)(key & 8191u);
  }
  __syncthreads();

  // ---- Phase C: gather winners + loss + in-place substitute ----
  float lsum = 0.0f;
  {
    const int r = tid & 31, seg = tid >> 5;  // conflict-free LDS (r varies)
    const int code = (int)fi[r];
    const float* cp = cb + (size_t)code * CCDIM + seg * 32;
#pragma unroll
    for (int j = 0; j < 8; ++j) {
      const float4 v = *(const float4*)(cp + j * 4);
      const int c = seg * 32 + j * 4;
      float dd;
      dd = v.x - xt[r][c + 0]; lsum = fmaf(dd, dd, lsum); xt[r][c + 0] = v.x;
      dd = v.y - xt[r][c + 1]; lsum = fmaf(dd, dd, lsum); xt[r][c + 1] = v.y;
      dd = v.z - xt[r][c + 2]; lsum = fmaf(dd, dd, lsum); xt[r][c + 2] = v.z;
      dd = v.w - xt[r][c + 3]; lsum = fmaf(dd, dd, lsum); xt[r][c + 3] = v.w;
    }
  }
  __syncthreads();

  // ---- write out (coalesced 128 B segments) ----
  {
    const int hwoff = tid & 31, cg = tid >> 5;
    const size_t obase = (size_t)b * (CCDIM * HWP) + hw0 + hwoff;
#pragma unroll 8
    for (int i = 0; i < 32; ++i) {
      const int c = cg * 32 + i;
      out[obase + (size_t)c * HWP] = xt[hwoff][c];
    }
  }

  // ---- loss reduction + last-block finalize ----
#pragma unroll
  for (int off = 32; off > 0; off >>= 1) lsum += __shfl_down(lsum, off, 64);
  if ((tid & 63) == 0) wsum[tid >> 6] = lsum;
  __syncthreads();
  if (tid == 0) {
    atomicAdd(accp, wsum[0] + wsum[1] + wsum[2] + wsum[3]);
    __threadfence();
    const u32 old = atomicAdd(cntp, 1u);
    if (old == gridDim.x - 1) {  // last block: finalize losses
      const float tot = atomicAdd(accp, 0.0f);
      const float mean = tot * (1.0f / (float)((size_t)NPOS * CCDIM));
      out[(size_t)NPOS * CCDIM] = mean;
      out[(size_t)NPOS * CCDIM + 1] = mean;
    }
  }
}

extern "C" void kernel_launch(void* const* d_in, const int* in_sizes, int n_in,
                              void* d_out, int out_size, void* d_ws,
                              size_t ws_size, hipStream_t stream) {
  (void)in_sizes;
  (void)n_in;
  (void)out_size;
  (void)ws_size;
  const float* x = (const float*)d_in[0];
  const float* cb = (const float*)d_in[1];
  float* out = (float*)d_out;

  uint8_t* ws = (uint8_t*)d_ws;
  float* e2 = (float*)(ws + 0);               // 32 KB
  u64* part = (u64*)(ws + (1ull << 20));      // 8.4 MB (64*NPOS u64)
  u16* xh = (u16*)(ws + (10ull << 20));       // 8.4 MB
  u16* ch = (u16*)(ws + (20ull << 20));       // 4.2 MB
  float* acc = (float*)(ws + (25ull << 20));  // 4 B
  u32* cnt = (u32*)(ws + (25ull << 20) + 128);

  pack_all<<<3072, 256, 0, stream>>>(x, cb, xh, ch, e2, acc, cnt);
  gemm_argmin<<<dim3(NPOS / 128, KC / 128), 256, 0, stream>>>(xh, ch, e2, part);
  merge_gather<<<NPOS / 32, 256, 0, stream>>>(part, x, cb, e2, out, acc, cnt);
}